// Round 4
// baseline (479.029 us; speedup 1.0000x reference)
//
#include <hip/hip_runtime.h>
#include <hip/hip_bf16.h>

// PLIF forward: v += x_t; spike = (v - 1 > 0); v -= spike * 1.0
// x: [T=16, N] fp32, out: spikes [T=16, N] fp32. N = B*C*H*W = 4,194,304.
//
// Persistent software-pipelined version:
//  - grid = n4 / (256*ITERS) blocks, every wave resident for the whole kernel
//  - double-buffered 8-plane register groups: while computing planes 0..7
//    (buf A) the loads for planes 8..15 (buf B) and the next position's A
//    are already in flight -> continuous memory issue, cold-start latency
//    paid once per wave, not once per position.
//  - loads are regular (x is L3-resident from the harness's d_in restore);
//    stores are nontemporal (out is touch-once; don't evict x from L3).

#ifndef PLIF_T
#define PLIF_T 16
#endif

typedef float f32x4 __attribute__((ext_vector_type(4)));

#define HALF_T 8
#define ITERS 4

__device__ __forceinline__ void plif_step8(f32x4& v, const f32x4* __restrict__ buf,
                                           f32x4* __restrict__ out, size_t n4,
                                           size_t i, int tbase) {
    #pragma unroll
    for (int k = 0; k < HALF_T; ++k) {
        f32x4 xt = buf[k];
        v += xt;
        f32x4 s;
        s.x = (v.x > 1.0f) ? 1.0f : 0.0f;
        s.y = (v.y > 1.0f) ? 1.0f : 0.0f;
        s.z = (v.z > 1.0f) ? 1.0f : 0.0f;
        s.w = (v.w > 1.0f) ? 1.0f : 0.0f;
        v -= s;
        __builtin_nontemporal_store(s, &out[(size_t)(tbase + k) * n4 + i]);
    }
}

__device__ __forceinline__ void load8(f32x4* __restrict__ buf,
                                      const f32x4* __restrict__ x, size_t n4,
                                      size_t i, int tbase) {
    #pragma unroll
    for (int k = 0; k < HALF_T; ++k) {
        buf[k] = x[(size_t)(tbase + k) * n4 + i];
    }
}

__global__ __launch_bounds__(256) void plif_fwd_pipelined(
    const f32x4* __restrict__ x, f32x4* __restrict__ out, int n4_i) {
    const size_t n4 = (size_t)n4_i;
    const size_t stride = (size_t)gridDim.x * blockDim.x;
    size_t i = (size_t)blockIdx.x * blockDim.x + threadIdx.x;

    f32x4 bufA[HALF_T];
    f32x4 bufB[HALF_T];

    // Prologue: planes 0..7 of first position.
    load8(bufA, x, n4, i, 0);

    #pragma unroll
    for (int it = 0; it < ITERS - 1; ++it) {
        f32x4 v = (f32x4)(0.f, 0.f, 0.f, 0.f);
        load8(bufB, x, n4, i, HALF_T);            // planes 8..15, current pos
        plif_step8(v, bufA, out, n4, i, 0);       // consume A (waits), store
        load8(bufA, x, n4, i + stride, 0);        // planes 0..7, next pos
        plif_step8(v, bufB, out, n4, i, HALF_T);  // consume B (waits), store
        i += stride;
    }

    // Epilogue: last position, no next-position prefetch.
    {
        f32x4 v = (f32x4)(0.f, 0.f, 0.f, 0.f);
        load8(bufB, x, n4, i, HALF_T);
        plif_step8(v, bufA, out, n4, i, 0);
        plif_step8(v, bufB, out, n4, i, HALF_T);
    }
}

// Fallback (round-3 kernel) for shapes that don't divide evenly.
__global__ __launch_bounds__(256) void plif_fwd_simple(
    const f32x4* __restrict__ x, f32x4* __restrict__ out, int n4) {
    int i = blockIdx.x * blockDim.x + threadIdx.x;
    if (i >= n4) return;
    f32x4 xt[PLIF_T];
    #pragma unroll
    for (int t = 0; t < PLIF_T; ++t)
        xt[t] = x[(size_t)t * (size_t)n4 + (size_t)i];
    f32x4 v = (f32x4)(0.f, 0.f, 0.f, 0.f);
    #pragma unroll
    for (int t = 0; t < PLIF_T; ++t) {
        v += xt[t];
        f32x4 s;
        s.x = (v.x > 1.0f) ? 1.0f : 0.0f;
        s.y = (v.y > 1.0f) ? 1.0f : 0.0f;
        s.z = (v.z > 1.0f) ? 1.0f : 0.0f;
        s.w = (v.w > 1.0f) ? 1.0f : 0.0f;
        v -= s;
        __builtin_nontemporal_store(s, &out[(size_t)t * (size_t)n4 + (size_t)i]);
    }
}

extern "C" void kernel_launch(void* const* d_in, const int* in_sizes, int n_in,
                              void* d_out, int out_size, void* d_ws, size_t ws_size,
                              hipStream_t stream) {
    const float* x = (const float*)d_in[0];
    float* out = (float*)d_out;

    const int total = in_sizes[0];          // T * N
    const int n = total / PLIF_T;           // spatial elements per timestep
    const int n4 = n / 4;                   // float4 groups per timestep

    const int block = 256;
    const int chunk = block * ITERS;

    if (n4 % chunk == 0) {
        const int grid = n4 / chunk;        // 1024 for the reference shape
        plif_fwd_pipelined<<<grid, block, 0, stream>>>(
            (const f32x4*)x, (f32x4*)out, n4);
    } else {
        const int grid = (n4 + block - 1) / block;
        plif_fwd_simple<<<grid, block, 0, stream>>>(
            (const f32x4*)x, (f32x4*)out, n4);
    }
}